// Round 2
// baseline (410.573 us; speedup 1.0000x reference)
//
#include <hip/hip_runtime.h>
#include <hip/hip_fp16.h>
#include <cstdint>

#define DEV static __device__ __forceinline__

typedef _Float16 f16x2 __attribute__((ext_vector_type(2)));
typedef _Float16 f16x8 __attribute__((ext_vector_type(8)));
typedef float    f32x4 __attribute__((ext_vector_type(4)));

DEV float fdot2u(uint32_t a, uint32_t b, float c){
  union U { uint32_t u; f16x2 h; };
  U ua; ua.u = a; U ub; ub.u = b;
#if __has_builtin(__builtin_amdgcn_fdot2)
  return __builtin_amdgcn_fdot2(ua.h, ub.h, c, false);
#else
  return c + (float)ua.h[0]*(float)ub.h[0] + (float)ua.h[1]*(float)ub.h[1];
#endif
}

DEV float dot4(uint4 x, uint4 w, float a){
  a = fdot2u(x.x, w.x, a); a = fdot2u(x.y, w.y, a);
  a = fdot2u(x.z, w.z, a); a = fdot2u(x.w, w.w, a);
  return a;
}

DEV float wsum64(float v){
  #pragma unroll
  for (int o = 32; o; o >>= 1) v += __shfl_xor(v, o);
  return v;
}

DEV uint32_t pack2h(float a, float b){
  __half ha = __float2half(a), hb = __float2half(b);
  return (uint32_t)__half_as_ushort(ha) | ((uint32_t)__half_as_ushort(hb) << 16);
}

// pack (v_even, v_odd) from lane pairs; result valid on even lane only
DEV uint32_t packsh(float v){
  float o = __shfl_xor(v, 1);
  return pack2h(v, o);
}

DEV uint4 packrow8(const float* p){
  uint4 r;
  r.x = pack2h(p[0], p[1]); r.y = pack2h(p[2], p[3]);
  r.z = pack2h(p[4], p[5]); r.w = pack2h(p[6], p[7]);
  return r;
}

// ---------------- merged: input LayerNorm (blocks < 32768) + weight repack (rest) ----------------
__global__ __launch_bounds__(256) void k_lntr(
  const float* __restrict__ xin, const float* __restrict__ lng,
  const float* __restrict__ lnb, uint32_t* __restrict__ xhat,
  const float* __restrict__ wq, const float* __restrict__ wv,
  const float* __restrict__ wih, const float* __restrict__ whh,
  const float* __restrict__ w1, const float* __restrict__ w2,
  const float* __restrict__ wk,
  uint4* __restrict__ WQp4, uint4* __restrict__ WVp4,
  uint4* __restrict__ WIHp4, uint4* __restrict__ WHHp4,
  uint4* __restrict__ W1p4, uint4* __restrict__ W2p4,
  uint4* __restrict__ WKp4)
{
  if (blockIdx.x >= 32768){
    int u = (blockIdx.x - 32768) * 256 + threadIdx.x;
    if (u < 8192){                                  // wv: N=256 K=256
      int e4 = u >> 8, n = u & 255;
      WVp4[u] = packrow8(wv + n*256 + 8*e4);
    } else if (u < 32768){                          // wih: N=768 K=256
      int v = u - 8192; int e4 = v / 768, n = v - e4*768;
      WIHp4[v] = packrow8(wih + n*256 + 8*e4);
    } else if (u < 57344){                          // whh
      int v = u - 32768; int e4 = v / 768, n = v - e4*768;
      WHHp4[v] = packrow8(whh + n*256 + 8*e4);
    } else if (u < 73728){                          // w1: N=512 K=256
      int v = u - 57344; int e4 = v >> 9, n = v & 511;
      W1p4[v] = packrow8(w1 + n*256 + 8*e4);
    } else if (u < 90112){                          // w2: N=256 K=512
      int v = u - 73728; int e4 = v >> 8, n = v & 255;
      W2p4[v] = packrow8(w2 + n*512 + 8*e4);
    } else if (u < 98304){                          // wq: N=256 K=256
      int v = u - 90112; int e4 = v >> 8, n = v & 255;
      WQp4[v] = packrow8(wq + n*256 + 8*e4);
    } else if (u < 106496){                         // wk strided: WKp4[d4][c]
      int v = u - 98304; int d4 = v >> 8, c = v & 255;
      uint4 r;
      r.x = pack2h(wk[(8*d4+0)*256 + c], wk[(8*d4+1)*256 + c]);
      r.y = pack2h(wk[(8*d4+2)*256 + c], wk[(8*d4+3)*256 + c]);
      r.z = pack2h(wk[(8*d4+4)*256 + c], wk[(8*d4+5)*256 + c]);
      r.w = pack2h(wk[(8*d4+6)*256 + c], wk[(8*d4+7)*256 + c]);
      WKp4[v] = r;
    }
    return;
  }
  int row = blockIdx.x * 4 + (threadIdx.x >> 6);
  int lane = threadIdx.x & 63;
  const float4 xv = ((const float4*)(xin + (size_t)row * 256))[lane];
  float s1 = wsum64(xv.x + xv.y + xv.z + xv.w);
  float s2 = wsum64(xv.x*xv.x + xv.y*xv.y + xv.z*xv.z + xv.w*xv.w);
  float m = s1 * (1.0f/256.0f);
  float var = s2 * (1.0f/256.0f) - m*m;
  float rstd = rsqrtf(var + 1e-5f);
  float4 gv = ((const float4*)lng)[lane];
  float4 bv = ((const float4*)lnb)[lane];
  float y0 = (xv.x - m)*rstd*gv.x + bv.x;
  float y1 = (xv.y - m)*rstd*gv.y + bv.y;
  float y2 = (xv.z - m)*rstd*gv.z + bv.z;
  float y3 = (xv.w - m)*rstd*gv.w + bv.w;
  ((uint2*)(xhat + (size_t)row * 128))[lane] = make_uint2(pack2h(y0,y1), pack2h(y2,y3));
}

// ---------------- fused slot-update chain ----------------
// 256 blocks x 512 threads; 1 row (b*8+s) per block.
// h = t>>8 is K-split half (or matrix selector for GRU); c = t&255.
// Reads per-chunk attn partials UAp[16][256][256] / ASp[16][256] (no atomics upstream).
template<int MODE>   // 0: init+q-chain, 1: chain+q-chain, 2: chain only (writes SDST=out, AS)
__global__ __launch_bounds__(512) void k_slot(
  const float* __restrict__ noise, const float* __restrict__ mu,
  const float* __restrict__ sigraw,
  const float* S0, float* SDST,
  const float* __restrict__ UAp, const float* __restrict__ ASp,
  float* __restrict__ AS,
  const uint4* __restrict__ WVp4, const float* __restrict__ bv,
  const uint4* __restrict__ WIHp4, const uint4* __restrict__ WHHp4,
  const float* __restrict__ bih, const float* __restrict__ bhh,
  const float* __restrict__ lmg, const float* __restrict__ lmb,
  const uint4* __restrict__ W1p4, const float* __restrict__ b1,
  const uint4* __restrict__ W2p4, const float* __restrict__ b2,
  const float* __restrict__ lsg, const float* __restrict__ lsb,
  const uint4* __restrict__ WQp4, const float* __restrict__ bq,
  const uint4* __restrict__ WKp4, const float* __restrict__ bk,
  uint32_t* __restrict__ QTH, float* __restrict__ CV)
{
  __shared__ float gx[768], gh[768];
  __shared__ float part[512];
  __shared__ uint4 hs4[32], un4[32], us4[32], sln4[32], q4[32];
  __shared__ uint4 hb4[64];
  __shared__ float redA[8], redB[8];

  const int t = threadIdx.x;
  const int h = t >> 8;           // 0/1
  const int c = t & 255;
  const int lane = t & 63;
  const int w8 = t >> 6;          // wave 0..7
  const int r = blockIdx.x;       // global row (b*8+s)
  const int b = r >> 3, s = r & 7;

  float snv = 0.f, spv = 0.f;

  if (MODE == 0){
    if (t < 256){
      float x = sigraw[c];
      float sp = (x > 20.0f) ? x : log1pf(__expf(x));
      snv = mu[c] + sp * noise[r*256 + c];
      SDST[r*256 + c] = snv;
    }
  } else {
    // ---- asum from 16 chunk partials ----
    if (w8 == 0){
      float v = (lane < 16) ? ASp[lane*256 + r] : 0.f;
      v += __shfl_xor(v, 1); v += __shfl_xor(v, 2);
      v += __shfl_xor(v, 4); v += __shfl_xor(v, 8);
      if (lane == 0) redA[0] = v;
    }
    __syncthreads();
    const float asum_r = redA[0];
    if (MODE == 2 && t == 0) AS[r] = asum_r;
    const float ainv = 1.0f / asum_r;
    float hv = 0.f;
    if (t < 256){
      hv = S0[r*256 + c];
      float us = 0.f;
      #pragma unroll
      for (int ch = 0; ch < 16; ++ch) us += UAp[ch*65536 + r*256 + c];
      float unv = us * ainv;
      uint32_t ph = packsh(hv), pu = packsh(unv);
      if (!(c & 1)){
        ((uint32_t*)hs4)[c>>1] = ph;
        ((uint32_t*)un4)[c>>1] = pu;
      }
    }
    __syncthreads();

    // ---- updates = (u/Asum) @ wv^T + bv : K-split by h ----
    {
      float a = 0.f;
      #pragma unroll 8
      for (int e4 = h*16; e4 < h*16 + 16; ++e4)
        a = dot4(un4[e4], WVp4[e4*256 + c], a);
      part[t] = a;
    }
    __syncthreads();
    if (t < 256){
      float us = part[t] + part[t + 256] + bv[c];
      uint32_t p = packsh(us);
      if (!(c & 1)) ((uint32_t*)us4)[c>>1] = p;
    }
    __syncthreads();

    // ---- GRU gates: h=0 -> gx (input us4, W_ih), h=1 -> gh (input hs4, W_hh) ----
    {
      const uint4* IN4 = h ? hs4 : us4;
      const uint4* WP = h ? WHHp4 : WIHp4;
      float a0 = 0.f, a1 = 0.f, a2 = 0.f;
      #pragma unroll 8
      for (int e4 = 0; e4 < 32; ++e4){
        uint4 x = IN4[e4];
        a0 = dot4(x, WP[e4*768 + c], a0);
        a1 = dot4(x, WP[e4*768 + 256 + c], a1);
        a2 = dot4(x, WP[e4*768 + 512 + c], a2);
      }
      float* OUT = h ? gh : gx;
      OUT[c] = a0; OUT[256 + c] = a1; OUT[512 + c] = a2;
    }
    __syncthreads();

    // ---- gate math + LN_m (t<256) ----
    if (t < 256){
      float xr = gx[c]     + bih[c];
      float xz = gx[256+c] + bih[256+c];
      float xn = gx[512+c] + bih[512+c];
      float hr = gh[c]     + bhh[c];
      float hz = gh[256+c] + bhh[256+c];
      float hn = gh[512+c] + bhh[512+c];
      float rg = 1.f/(1.f + __expf(-(xr + hr)));
      float zg = 1.f/(1.f + __expf(-(xz + hz)));
      float ng = tanhf(xn + rg*hn);
      spv = (1.f - zg)*ng + zg*hv;
      float a = wsum64(spv), bs = wsum64(spv*spv);
      if (lane == 0){ redA[w8] = a; redB[w8] = bs; }
    }
    __syncthreads();
    {
      float s1 = redA[0]+redA[1]+redA[2]+redA[3];
      float s2 = redB[0]+redB[1]+redB[2]+redB[3];
      float m = s1*(1.f/256.f), var = s2*(1.f/256.f) - m*m;
      float rstd = rsqrtf(var + 1e-5f);
      if (t < 256){
        float slv = (spv - m)*rstd*lmg[c] + lmb[c];
        uint32_t p = packsh(slv);
        if (!(c & 1)) ((uint32_t*)sln4)[c>>1] = p;
      }
    }
    __syncthreads();

    // ---- hmlp = relu(sln @ w1^T + b1): col = t (0..511) ----
    {
      float a = 0.f;
      #pragma unroll 8
      for (int e4 = 0; e4 < 32; ++e4)
        a = dot4(sln4[e4], W1p4[e4*512 + t], a);
      float hval = fmaxf(a + b1[t], 0.f);
      float o = __shfl_xor(hval, 1);
      if (!(t & 1)) ((uint32_t*)hb4)[t>>1] = pack2h(hval, o);
    }
    __syncthreads();

    // ---- slots = smid + h @ w2^T + b2 : K=512, K-split by h ----
    {
      float a = 0.f;
      #pragma unroll 8
      for (int e4 = h*32; e4 < h*32 + 32; ++e4)
        a = dot4(hb4[e4], W2p4[e4*256 + c], a);
      part[t] = a;
    }
    __syncthreads();
    if (t < 256){
      snv = spv + part[t] + part[t + 256] + b2[c];
      SDST[r*256 + c] = snv;
    }
  }

  if (MODE != 2){
    // ---- LN_s(new slots) ----
    if (t < 256){
      float a = wsum64(snv), bs = wsum64(snv*snv);
      if (lane == 0){ redA[w8] = a; redB[w8] = bs; }
    }
    __syncthreads();
    {
      float s1 = redA[0]+redA[1]+redA[2]+redA[3];
      float s2 = redB[0]+redB[1]+redB[2]+redB[3];
      float m = s1*(1.f/256.f), var = s2*(1.f/256.f) - m*m;
      float rstd = rsqrtf(var + 1e-5f);
      if (t < 256){
        float slv = (snv - m)*rstd*lsg[c] + lsb[c];
        uint32_t p = packsh(slv);
        if (!(c & 1)) ((uint32_t*)sln4)[c>>1] = p;
      }
    }
    __syncthreads();

    // ---- q = slnS @ wq^T + bq : K-split by h ----
    {
      float a = 0.f;
      #pragma unroll 8
      for (int e4 = h*16; e4 < h*16 + 16; ++e4)
        a = dot4(sln4[e4], WQp4[e4*256 + c], a);
      part[t] = a;
    }
    __syncthreads();
    if (t < 256){
      float qv = part[t] + part[t + 256] + bq[c];
      float p = wsum64(bk[c] * qv);
      if (lane == 0) redA[w8] = p;
      uint32_t pk = packsh(qv);
      if (!(c & 1)) ((uint32_t*)q4)[c>>1] = pk;
    }
    __syncthreads();
    {
      float cv = redA[0]+redA[1]+redA[2]+redA[3];
      if (t == 0) CV[r] = cv;
    }

    // ---- qt = q @ wk : K-split by h ----
    {
      float a = 0.f;
      #pragma unroll 8
      for (int e4 = h*16; e4 < h*16 + 16; ++e4)
        a = dot4(q4[e4], WKp4[e4*256 + c], a);
      part[t] = a;
    }
    __syncthreads();
    if (t < 256){
      float qtv = part[t] + part[t + 256];
      uint32_t p = packsh(qtv);
      if (!(c & 1)) QTH[b*1024 + (c>>1)*8 + s] = p;
    }
  }
}

// ---------------- fused attention pass (MFMA logits + register-outer-product updates) ----
// grid (16,32): chunk, b. 256 rows/block in 4 subtiles of 64 rows.
// T14 async-stage: subtile st+1 loaded to registers before the updates loop of st
// (HBM/L3 latency hides under ~1300 VALU cycles), ds_written after the barrier.
// LDS layout: logical quad q of row r stored at physical quad q ^ (r&7) (XOR swizzle),
// so MFMA A-reads (b128) and updates b64 reads are phase-conflict-free.
// Partial outputs: plain stores to per-chunk UAp/ASp (no atomics).
template<bool LAST>
__global__ __launch_bounds__(256, 2) void k_attn(
  const uint32_t* __restrict__ xhat,
  const uint32_t* __restrict__ qtpk, const float* __restrict__ cvec,
  float* __restrict__ UAp, float* __restrict__ ASp,
  float* __restrict__ attn_out)
{
  __shared__ uint32_t xs[8192];          // 64 rows x 128 words, quad-swizzled
  __shared__ uint32_t qs[1024];          // qt packed pairs [dp*8 + s]
  __shared__ float attn_lds[64][16];     // f32 attn, cols 8..15 = scratch
  __shared__ float up_lds[8][256];       // cross-wave update reduction
  __shared__ float as_red[4][8];         // per-wave asum partials

  const int b = blockIdx.y, chunk = blockIdx.x;
  const int t = threadIdx.x;
  const int l = t & 63, w = t >> 6;      // lane, wave (4 waves)
  const int g = l >> 4, sl = l & 15;     // 16-lane group, in-group id

  const size_t base = (size_t)b*4096 + (size_t)chunk*256;

  uint4 stg[8];
  // --- prologue: reg-load subtile 0, qs, then ds_write subtile 0 ---
  #pragma unroll
  for (int i = 0; i < 8; ++i){
    int c16 = i*256 + t;
    int row = c16 >> 5, q = c16 & 31;
    stg[i] = *(const uint4*)(xhat + (base + row)*128 + q*4);
  }
  for (int i = t; i < 1024; i += 256) qs[i] = qtpk[b*1024 + i];
  #pragma unroll
  for (int i = 0; i < 8; ++i){
    int c16 = i*256 + t;
    int row = c16 >> 5, q = c16 & 31;
    *(uint4*)(xs + row*128 + ((q ^ (row & 7)) << 2)) = stg[i];
  }
  __syncthreads();

  // --- gather q B-frags from qs into registers (once per block) ---
  // b-frag for K-step kk: lane holds B[k=32kk+8g+j][col=sl], j=0..7
  uint4 bq[8];
  #pragma unroll
  for (int kk = 0; kk < 8; ++kk){
    if (sl < 8){
      uint4 v;
      v.x = qs[(16*kk + 4*g + 0)*8 + sl];
      v.y = qs[(16*kk + 4*g + 1)*8 + sl];
      v.z = qs[(16*kk + 4*g + 2)*8 + sl];
      v.w = qs[(16*kk + 4*g + 3)*8 + sl];
      bq[kk] = v;
    } else bq[kk] = make_uint4(0u,0u,0u,0u);
  }
  const float cv = (sl < 8) ? cvec[b*8 + sl] : 0.f;

  float up[8][4];                         // [slot][col] register accumulators
  #pragma unroll
  for (int s = 0; s < 8; ++s){ up[s][0]=0.f; up[s][1]=0.f; up[s][2]=0.f; up[s][3]=0.f; }
  float asl_acc = 0.f;

  for (int st = 0; st < 4; ++st){
    const int L0 = 16*w;

    // ---- logits tile [16 rows x 16 slots] via 8 MFMA K-steps ----
    f32x4 acc; acc[0]=0.f; acc[1]=0.f; acc[2]=0.f; acc[3]=0.f;
    const int rowA = L0 + sl;             // A-frag row (m = sl)
    #pragma unroll
    for (int kk = 0; kk < 8; ++kk){
      uint4 av = *(const uint4*)(xs + rowA*128 + (((4*kk + g) ^ (rowA & 7)) << 2));
      union { uint4 u; f16x8 h; } A, B;
      A.u = av; B.u = bq[kk];
      acc = __builtin_amdgcn_mfma_f32_16x16x32_f16(A.h, B.h, acc, 0, 0, 0);
    }

    // ---- softmax over slots: D lane holds (slot=sl, rows L0+4g+reg) ----
    #pragma unroll
    for (int reg = 0; reg < 4; ++reg){
      float d = (acc[reg] + cv) * 0.0625f;
      float m = d;
      m = fmaxf(m, __shfl_xor(m, 1));
      m = fmaxf(m, __shfl_xor(m, 2));
      m = fmaxf(m, __shfl_xor(m, 4));
      float e = __expf(d - m);
      float ssum = e;
      ssum += __shfl_xor(ssum, 1);
      ssum += __shfl_xor(ssum, 2);
      ssum += __shfl_xor(ssum, 4);
      float a = e / ssum + 1e-8f;
      asl_acc += a;                       // garbage for sl>=8, never used
      attn_lds[L0 + 4*g + reg][sl] = a;   // sl>=8 writes scratch cols
    }

    // ---- T14: issue next-subtile global loads BEFORE the updates loop ----
    if (st < 3){
      const size_t g2 = base + (size_t)(st+1)*64;
      #pragma unroll
      for (int i = 0; i < 8; ++i){
        int c16 = i*256 + t;
        int row = c16 >> 5, q = c16 & 31;
        stg[i] = *(const uint4*)(xhat + (g2 + row)*128 + q*4);
      }
    }

    // ---- updates: wave w owns rows L0..L0+15; lane owns cols 4l..4l+3 ----
    #pragma unroll 4
    for (int rr = 0; rr < 16; ++rr){
      const int row = L0 + rr;
      const uint32_t* xp = xs + row*128 + ((((l>>1) ^ (row & 7)) << 2) | ((l & 1) << 1));
      uint2 xv = *(const uint2*)xp;
      float x0 = __half2float(__ushort_as_half((unsigned short)(xv.x & 0xffff)));
      float x1 = __half2float(__ushort_as_half((unsigned short)(xv.x >> 16)));
      float x2 = __half2float(__ushort_as_half((unsigned short)(xv.y & 0xffff)));
      float x3 = __half2float(__ushort_as_half((unsigned short)(xv.y >> 16)));
      const float4 a0 = *(const float4*)&attn_lds[row][0];
      const float4 a1 = *(const float4*)&attn_lds[row][4];
      float as8[8] = {a0.x, a0.y, a0.z, a0.w, a1.x, a1.y, a1.z, a1.w};
      #pragma unroll
      for (int s = 0; s < 8; ++s){
        up[s][0] += as8[s]*x0; up[s][1] += as8[s]*x1;
        up[s][2] += as8[s]*x2; up[s][3] += as8[s]*x3;
      }
    }

    if (LAST){
      __syncthreads();                    // all waves' attn_lds visible
      int row = t >> 2, s0 = (t & 3)*2;
      float2 v = *(const float2*)&attn_lds[row][s0];
      *(float2*)(attn_out + (base + (size_t)st*64 + row)*8 + s0) = v;
    }

    if (st < 3){
      __syncthreads();                    // all done reading xs(st)
      #pragma unroll
      for (int i = 0; i < 8; ++i){
        int c16 = i*256 + t;
        int row = c16 >> 5, q = c16 & 31;
        *(uint4*)(xs + row*128 + ((q ^ (row & 7)) << 2)) = stg[i];
      }
      __syncthreads();                    // xs(st+1) ready
    }
  }

  // ---- asum partials: per-wave reduce over g, stash in LDS ----
  {
    float v = asl_acc;
    v += __shfl_xor(v, 16);
    v += __shfl_xor(v, 32);
    if (l < 8) as_red[w][l] = v;
  }

  // ---- cross-wave reduction of up into up_lds (4 turns), then plain stores ----
  __syncthreads();
  #pragma unroll
  for (int ww = 0; ww < 4; ++ww){
    if (w == ww){
      #pragma unroll
      for (int s = 0; s < 8; ++s){
        float4* dst = (float4*)&up_lds[s][l*4];
        float4 v = make_float4(up[s][0], up[s][1], up[s][2], up[s][3]);
        if (ww){ float4 o = *dst; v.x += o.x; v.y += o.y; v.z += o.z; v.w += o.w; }
        *dst = v;
      }
    }
    __syncthreads();
  }
  #pragma unroll
  for (int s = 0; s < 8; ++s)
    UAp[(size_t)chunk*65536 + (size_t)(b*8 + s)*256 + t] = up_lds[s][t];
  if (t < 8)
    ASp[chunk*256 + b*8 + t] = as_red[0][t] + as_red[1][t] + as_red[2][t] + as_red[3][t];
}

// ---------------- final output: attn renormalize only (slots written by k_slot<2>) ----------------
__global__ __launch_bounds__(256) void k_out(
  const float* __restrict__ AS, float* __restrict__ out)
{
  int j = blockIdx.x * 256 + threadIdx.x;   // 0..1048575
  int b = j >> 15;
  int s = j & 7;
  out[65536 + j] = out[65536 + j] * (1.0f / AS[b*8 + s]);
}

extern "C" void kernel_launch(void* const* d_in, const int* in_sizes, int n_in,
                              void* d_out, int out_size, void* d_ws, size_t ws_size,
                              hipStream_t stream) {
  const float* inputs = (const float*)d_in[0];
  const float* noise  = (const float*)d_in[1];
  const float* mu     = (const float*)d_in[2];
  const float* sigraw = (const float*)d_in[3];
  const float* lng    = (const float*)d_in[4];
  const float* lnb    = (const float*)d_in[5];
  const float* lsg    = (const float*)d_in[6];
  const float* lsb    = (const float*)d_in[7];
  const float* lmg    = (const float*)d_in[8];
  const float* lmb    = (const float*)d_in[9];
  const float* wq     = (const float*)d_in[10];
  const float* bq     = (const float*)d_in[11];
  const float* wk     = (const float*)d_in[12];
  const float* bk     = (const float*)d_in[13];
  const float* wv     = (const float*)d_in[14];
  const float* bv     = (const float*)d_in[15];
  const float* wih    = (const float*)d_in[16];
  const float* whh    = (const float*)d_in[17];
  const float* bih    = (const float*)d_in[18];
  const float* bhh    = (const float*)d_in[19];
  const float* w1     = (const float*)d_in[20];
  const float* b1     = (const float*)d_in[21];
  const float* w2     = (const float*)d_in[22];
  const float* b2     = (const float*)d_in[23];
  float* out = (float*)d_out;

  char* w = (char*)d_ws;
  size_t o = 0;
  uint32_t* XH = (uint32_t*)w;  o += 67108864;
  uint32_t* QT = (uint32_t*)(w + o); o += 131072;
  float* CV  = (float*)(w + o); o += 1024;
  float* AS  = (float*)(w + o); o += 1024;
  float* S0  = (float*)(w + o); o += 262144;
  uint4* WQp = (uint4*)(w + o); o += 131072;
  uint4* WVp = (uint4*)(w + o); o += 131072;
  uint4* WIHp= (uint4*)(w + o); o += 393216;
  uint4* WHHp= (uint4*)(w + o); o += 393216;
  uint4* W1p = (uint4*)(w + o); o += 262144;
  uint4* W2p = (uint4*)(w + o); o += 262144;
  uint4* WKp = (uint4*)(w + o); o += 131072;
  float* UAp = (float*)(w + o); o += 4194304;   // [16][256][256] f32
  float* ASp = (float*)(w + o); o += 16384;     // [16][256] f32

  k_lntr<<<33184, 256, 0, stream>>>(inputs, lng, lnb, XH,
                                    wq, wv, wih, whh, w1, w2, wk,
                                    WQp, WVp, WIHp, WHHp, W1p, W2p, WKp);
  k_slot<0><<<256, 512, 0, stream>>>(noise, mu, sigraw, S0, S0, UAp, ASp, AS,
      WVp, bv, WIHp, WHHp, bih, bhh, lmg, lmb, W1p, b1, W2p, b2,
      lsg, lsb, WQp, bq, WKp, bk, QT, CV);

  dim3 ga(16, 32);
  for (int it = 0; it < 3; ++it){
    if (it == 2) k_attn<true ><<<ga, 256, 0, stream>>>(XH, QT, CV, UAp, ASp, out + 65536);
    else         k_attn<false><<<ga, 256, 0, stream>>>(XH, QT, CV, UAp, ASp, out + 65536);
    if (it < 2)
      k_slot<1><<<256, 512, 0, stream>>>(noise, mu, sigraw, S0, S0, UAp, ASp, AS,
          WVp, bv, WIHp, WHHp, bih, bhh, lmg, lmb, W1p, b1, W2p, b2,
          lsg, lsb, WQp, bq, WKp, bk, QT, CV);
    else
      k_slot<2><<<256, 512, 0, stream>>>(noise, mu, sigraw, S0, out, UAp, ASp, AS,
          WVp, bv, WIHp, WHHp, bih, bhh, lmg, lmb, W1p, b1, W2p, b2,
          lsg, lsb, WQp, bq, WKp, bk, QT, CV);
  }
  k_out<<<4096, 256, 0, stream>>>(AS, out);
}

// Round 3
// 373.564 us; speedup vs baseline: 1.0991x; 1.0991x over previous
//
#include <hip/hip_runtime.h>
#include <hip/hip_fp16.h>
#include <cstdint>

#define DEV static __device__ __forceinline__

typedef _Float16 f16x2 __attribute__((ext_vector_type(2)));
typedef _Float16 f16x8 __attribute__((ext_vector_type(8)));
typedef float    f32x4 __attribute__((ext_vector_type(4)));

DEV float fdot2u(uint32_t a, uint32_t b, float c){
  union U { uint32_t u; f16x2 h; };
  U ua; ua.u = a; U ub; ub.u = b;
#if __has_builtin(__builtin_amdgcn_fdot2)
  return __builtin_amdgcn_fdot2(ua.h, ub.h, c, false);
#else
  return c + (float)ua.h[0]*(float)ub.h[0] + (float)ua.h[1]*(float)ub.h[1];
#endif
}

DEV float dot4(uint4 x, uint4 w, float a){
  a = fdot2u(x.x, w.x, a); a = fdot2u(x.y, w.y, a);
  a = fdot2u(x.z, w.z, a); a = fdot2u(x.w, w.w, a);
  return a;
}

DEV float wsum64(float v){
  #pragma unroll
  for (int o = 32; o; o >>= 1) v += __shfl_xor(v, o);
  return v;
}

DEV uint32_t pack2h(float a, float b){
  __half ha = __float2half(a), hb = __float2half(b);
  return (uint32_t)__half_as_ushort(ha) | ((uint32_t)__half_as_ushort(hb) << 16);
}

// pack (v_even, v_odd) from lane pairs; result valid on even lane only
DEV uint32_t packsh(float v){
  float o = __shfl_xor(v, 1);
  return pack2h(v, o);
}

DEV uint4 packrow8(const float* p){
  uint4 r;
  r.x = pack2h(p[0], p[1]); r.y = pack2h(p[2], p[3]);
  r.z = pack2h(p[4], p[5]); r.w = pack2h(p[6], p[7]);
  return r;
}

// async global->LDS, 16B per lane. LDS dest = wave-uniform base + lane*16.
DEV void gld16(const void* g, void* l){
  __builtin_amdgcn_global_load_lds(
      (const __attribute__((address_space(1))) void*)g,
      (__attribute__((address_space(3))) void*)l, 16, 0, 0);
}

// ---------------- merged: input LayerNorm (blocks < 32768) + weight repack (rest) ----------------
__global__ __launch_bounds__(256) void k_lntr(
  const float* __restrict__ xin, const float* __restrict__ lng,
  const float* __restrict__ lnb, uint32_t* __restrict__ xhat,
  const float* __restrict__ wq, const float* __restrict__ wv,
  const float* __restrict__ wih, const float* __restrict__ whh,
  const float* __restrict__ w1, const float* __restrict__ w2,
  const float* __restrict__ wk,
  uint4* __restrict__ WQp4, uint4* __restrict__ WVp4,
  uint4* __restrict__ WIHp4, uint4* __restrict__ WHHp4,
  uint4* __restrict__ W1p4, uint4* __restrict__ W2p4,
  uint4* __restrict__ WKp4)
{
  if (blockIdx.x >= 32768){
    int u = (blockIdx.x - 32768) * 256 + threadIdx.x;
    if (u < 8192){                                  // wv: N=256 K=256
      int e4 = u >> 8, n = u & 255;
      WVp4[u] = packrow8(wv + n*256 + 8*e4);
    } else if (u < 32768){                          // wih: N=768 K=256
      int v = u - 8192; int e4 = v / 768, n = v - e4*768;
      WIHp4[v] = packrow8(wih + n*256 + 8*e4);
    } else if (u < 57344){                          // whh
      int v = u - 32768; int e4 = v / 768, n = v - e4*768;
      WHHp4[v] = packrow8(whh + n*256 + 8*e4);
    } else if (u < 73728){                          // w1: N=512 K=256
      int v = u - 57344; int e4 = v >> 9, n = v & 511;
      W1p4[v] = packrow8(w1 + n*256 + 8*e4);
    } else if (u < 90112){                          // w2: N=256 K=512
      int v = u - 73728; int e4 = v >> 8, n = v & 255;
      W2p4[v] = packrow8(w2 + n*512 + 8*e4);
    } else if (u < 98304){                          // wq: N=256 K=256
      int v = u - 90112; int e4 = v >> 8, n = v & 255;
      WQp4[v] = packrow8(wq + n*256 + 8*e4);
    } else if (u < 106496){                         // wk strided: WKp4[d4][c]
      int v = u - 98304; int d4 = v >> 8, c = v & 255;
      uint4 r;
      r.x = pack2h(wk[(8*d4+0)*256 + c], wk[(8*d4+1)*256 + c]);
      r.y = pack2h(wk[(8*d4+2)*256 + c], wk[(8*d4+3)*256 + c]);
      r.z = pack2h(wk[(8*d4+4)*256 + c], wk[(8*d4+5)*256 + c]);
      r.w = pack2h(wk[(8*d4+6)*256 + c], wk[(8*d4+7)*256 + c]);
      WKp4[v] = r;
    }
    return;
  }
  int row = blockIdx.x * 4 + (threadIdx.x >> 6);
  int lane = threadIdx.x & 63;
  const float4 xv = ((const float4*)(xin + (size_t)row * 256))[lane];
  float s1 = wsum64(xv.x + xv.y + xv.z + xv.w);
  float s2 = wsum64(xv.x*xv.x + xv.y*xv.y + xv.z*xv.z + xv.w*xv.w);
  float m = s1 * (1.0f/256.0f);
  float var = s2 * (1.0f/256.0f) - m*m;
  float rstd = rsqrtf(var + 1e-5f);
  float4 gv = ((const float4*)lng)[lane];
  float4 bv = ((const float4*)lnb)[lane];
  float y0 = (xv.x - m)*rstd*gv.x + bv.x;
  float y1 = (xv.y - m)*rstd*gv.y + bv.y;
  float y2 = (xv.z - m)*rstd*gv.z + bv.z;
  float y3 = (xv.w - m)*rstd*gv.w + bv.w;
  ((uint2*)(xhat + (size_t)row * 128))[lane] = make_uint2(pack2h(y0,y1), pack2h(y2,y3));
}

// ---------------- fused slot-update chain ----------------
// 256 blocks x 512 threads; 1 row (b*8+s) per block.
// h = t>>8 is K-split half (or matrix selector for GRU); c = t&255.
// Reads per-chunk attn partials UAp[16][256][256] / ASp[16][256] (no atomics upstream).
template<int MODE>   // 0: init+q-chain, 1: chain+q-chain, 2: chain only (writes SDST=out, AS)
__global__ __launch_bounds__(512) void k_slot(
  const float* __restrict__ noise, const float* __restrict__ mu,
  const float* __restrict__ sigraw,
  const float* S0, float* SDST,
  const float* __restrict__ UAp, const float* __restrict__ ASp,
  float* __restrict__ AS,
  const uint4* __restrict__ WVp4, const float* __restrict__ bv,
  const uint4* __restrict__ WIHp4, const uint4* __restrict__ WHHp4,
  const float* __restrict__ bih, const float* __restrict__ bhh,
  const float* __restrict__ lmg, const float* __restrict__ lmb,
  const uint4* __restrict__ W1p4, const float* __restrict__ b1,
  const uint4* __restrict__ W2p4, const float* __restrict__ b2,
  const float* __restrict__ lsg, const float* __restrict__ lsb,
  const uint4* __restrict__ WQp4, const float* __restrict__ bq,
  const uint4* __restrict__ WKp4, const float* __restrict__ bk,
  uint32_t* __restrict__ QTH, float* __restrict__ CV)
{
  __shared__ float gx[768], gh[768];
  __shared__ float part[512];
  __shared__ uint4 hs4[32], un4[32], us4[32], sln4[32], q4[32];
  __shared__ uint4 hb4[64];
  __shared__ float redA[8], redB[8];

  const int t = threadIdx.x;
  const int h = t >> 8;           // 0/1
  const int c = t & 255;
  const int lane = t & 63;
  const int w8 = t >> 6;          // wave 0..7
  const int r = blockIdx.x;       // global row (b*8+s)
  const int b = r >> 3, s = r & 7;

  float snv = 0.f, spv = 0.f;

  if (MODE == 0){
    if (t < 256){
      float x = sigraw[c];
      float sp = (x > 20.0f) ? x : log1pf(__expf(x));
      snv = mu[c] + sp * noise[r*256 + c];
      SDST[r*256 + c] = snv;
    }
  } else {
    // ---- asum from 16 chunk partials ----
    if (w8 == 0){
      float v = (lane < 16) ? ASp[lane*256 + r] : 0.f;
      v += __shfl_xor(v, 1); v += __shfl_xor(v, 2);
      v += __shfl_xor(v, 4); v += __shfl_xor(v, 8);
      if (lane == 0) redA[0] = v;
    }
    __syncthreads();
    const float asum_r = redA[0];
    if (MODE == 2 && t == 0) AS[r] = asum_r;
    const float ainv = 1.0f / asum_r;
    float hv = 0.f;
    if (t < 256){
      hv = S0[r*256 + c];
      float us = 0.f;
      #pragma unroll
      for (int ch = 0; ch < 16; ++ch) us += UAp[ch*65536 + r*256 + c];
      float unv = us * ainv;
      uint32_t ph = packsh(hv), pu = packsh(unv);
      if (!(c & 1)){
        ((uint32_t*)hs4)[c>>1] = ph;
        ((uint32_t*)un4)[c>>1] = pu;
      }
    }
    __syncthreads();

    // ---- updates = (u/Asum) @ wv^T + bv : K-split by h ----
    {
      float a = 0.f;
      #pragma unroll 8
      for (int e4 = h*16; e4 < h*16 + 16; ++e4)
        a = dot4(un4[e4], WVp4[e4*256 + c], a);
      part[t] = a;
    }
    __syncthreads();
    if (t < 256){
      float us = part[t] + part[t + 256] + bv[c];
      uint32_t p = packsh(us);
      if (!(c & 1)) ((uint32_t*)us4)[c>>1] = p;
    }
    __syncthreads();

    // ---- GRU gates: h=0 -> gx (input us4, W_ih), h=1 -> gh (input hs4, W_hh) ----
    {
      const uint4* IN4 = h ? hs4 : us4;
      const uint4* WP = h ? WHHp4 : WIHp4;
      float a0 = 0.f, a1 = 0.f, a2 = 0.f;
      #pragma unroll 8
      for (int e4 = 0; e4 < 32; ++e4){
        uint4 x = IN4[e4];
        a0 = dot4(x, WP[e4*768 + c], a0);
        a1 = dot4(x, WP[e4*768 + 256 + c], a1);
        a2 = dot4(x, WP[e4*768 + 512 + c], a2);
      }
      float* OUT = h ? gh : gx;
      OUT[c] = a0; OUT[256 + c] = a1; OUT[512 + c] = a2;
    }
    __syncthreads();

    // ---- gate math + LN_m (t<256) ----
    if (t < 256){
      float xr = gx[c]     + bih[c];
      float xz = gx[256+c] + bih[256+c];
      float xn = gx[512+c] + bih[512+c];
      float hr = gh[c]     + bhh[c];
      float hz = gh[256+c] + bhh[256+c];
      float hn = gh[512+c] + bhh[512+c];
      float rg = 1.f/(1.f + __expf(-(xr + hr)));
      float zg = 1.f/(1.f + __expf(-(xz + hz)));
      float ng = tanhf(xn + rg*hn);
      spv = (1.f - zg)*ng + zg*hv;
      float a = wsum64(spv), bs = wsum64(spv*spv);
      if (lane == 0){ redA[w8] = a; redB[w8] = bs; }
    }
    __syncthreads();
    {
      float s1 = redA[0]+redA[1]+redA[2]+redA[3];
      float s2 = redB[0]+redB[1]+redB[2]+redB[3];
      float m = s1*(1.f/256.f), var = s2*(1.f/256.f) - m*m;
      float rstd = rsqrtf(var + 1e-5f);
      if (t < 256){
        float slv = (spv - m)*rstd*lmg[c] + lmb[c];
        uint32_t p = packsh(slv);
        if (!(c & 1)) ((uint32_t*)sln4)[c>>1] = p;
      }
    }
    __syncthreads();

    // ---- hmlp = relu(sln @ w1^T + b1): col = t (0..511) ----
    {
      float a = 0.f;
      #pragma unroll 8
      for (int e4 = 0; e4 < 32; ++e4)
        a = dot4(sln4[e4], W1p4[e4*512 + t], a);
      float hval = fmaxf(a + b1[t], 0.f);
      float o = __shfl_xor(hval, 1);
      if (!(t & 1)) ((uint32_t*)hb4)[t>>1] = pack2h(hval, o);
    }
    __syncthreads();

    // ---- slots = smid + h @ w2^T + b2 : K=512, K-split by h ----
    {
      float a = 0.f;
      #pragma unroll 8
      for (int e4 = h*32; e4 < h*32 + 32; ++e4)
        a = dot4(hb4[e4], W2p4[e4*256 + c], a);
      part[t] = a;
    }
    __syncthreads();
    if (t < 256){
      snv = spv + part[t] + part[t + 256] + b2[c];
      SDST[r*256 + c] = snv;
    }
  }

  if (MODE != 2){
    // ---- LN_s(new slots) ----
    if (t < 256){
      float a = wsum64(snv), bs = wsum64(snv*snv);
      if (lane == 0){ redA[w8] = a; redB[w8] = bs; }
    }
    __syncthreads();
    {
      float s1 = redA[0]+redA[1]+redA[2]+redA[3];
      float s2 = redB[0]+redB[1]+redB[2]+redB[3];
      float m = s1*(1.f/256.f), var = s2*(1.f/256.f) - m*m;
      float rstd = rsqrtf(var + 1e-5f);
      if (t < 256){
        float slv = (snv - m)*rstd*lsg[c] + lsb[c];
        uint32_t p = packsh(slv);
        if (!(c & 1)) ((uint32_t*)sln4)[c>>1] = p;
      }
    }
    __syncthreads();

    // ---- q = slnS @ wq^T + bq : K-split by h ----
    {
      float a = 0.f;
      #pragma unroll 8
      for (int e4 = h*16; e4 < h*16 + 16; ++e4)
        a = dot4(sln4[e4], WQp4[e4*256 + c], a);
      part[t] = a;
    }
    __syncthreads();
    if (t < 256){
      float qv = part[t] + part[t + 256] + bq[c];
      float p = wsum64(bk[c] * qv);
      if (lane == 0) redA[w8] = p;
      uint32_t pk = packsh(qv);
      if (!(c & 1)) ((uint32_t*)q4)[c>>1] = pk;
    }
    __syncthreads();
    {
      float cv = redA[0]+redA[1]+redA[2]+redA[3];
      if (t == 0) CV[r] = cv;
    }

    // ---- qt = q @ wk : K-split by h ----
    {
      float a = 0.f;
      #pragma unroll 8
      for (int e4 = h*16; e4 < h*16 + 16; ++e4)
        a = dot4(q4[e4], WKp4[e4*256 + c], a);
      part[t] = a;
    }
    __syncthreads();
    if (t < 256){
      float qtv = part[t] + part[t + 256];
      uint32_t p = packsh(qtv);
      if (!(c & 1)) QTH[b*1024 + (c>>1)*8 + s] = p;
    }
  }
}

// ---------------- fused attention pass (MFMA logits + register-outer-product updates) ----
// grid (16,32): chunk, b. 256 rows/block in 4 subtiles of 64 rows.
// Staging: global_load_lds (direct-to-LDS, no VGPR round trip) with
// inverse-XOR-swizzled SOURCE address: physical quad pq holds logical quad
// pq ^ (row&7), so MFMA A-reads (b128) and updates b64 reads are conflict-free.
// Partial outputs: plain stores to per-chunk UAp/ASp (no atomics).
template<bool LAST>
__global__ __launch_bounds__(256) void k_attn(
  const uint32_t* __restrict__ xhat,
  const uint32_t* __restrict__ qtpk, const float* __restrict__ cvec,
  float* __restrict__ UAp, float* __restrict__ ASp,
  float* __restrict__ attn_out)
{
  __shared__ uint32_t xs[8192];          // 64 rows x 128 words, quad-swizzled
  __shared__ uint32_t qs[1024];          // qt packed pairs [dp*8 + s]
  __shared__ float attn_lds[64][16];     // f32 attn, cols 8..15 = scratch
  __shared__ float up_lds[8][256];       // cross-wave update reduction
  __shared__ float as_red[4][8];         // per-wave asum partials

  const int b = blockIdx.y, chunk = blockIdx.x;
  const int t = threadIdx.x;
  const int l = t & 63, w = t >> 6;      // lane, wave (4 waves)
  const int g = l >> 4, sl = l & 15;     // 16-lane group, in-group id

  const size_t base = (size_t)b*4096 + (size_t)chunk*256;

  for (int i = t; i < 1024; i += 256) qs[i] = qtpk[b*1024 + i];

  // --- stage one 64-row subtile: 32 x gload16 (8 per wave), 1KB each ---
  auto stage = [&](int st){
    const size_t gr0 = base + (size_t)st*64;
    #pragma unroll
    for (int i = 0; i < 8; ++i){
      int n  = w*8 + i;                  // covers local rows 2n, 2n+1
      int rl = 2*n + (l >> 5);
      int ql = (l & 31) ^ (rl & 7);      // inverse swizzle on SOURCE
      gld16(xhat + (gr0 + rl)*128 + ql*4, xs + n*256);
    }
  };

  stage(0);
  __syncthreads();   // drains vmcnt + lgkm: xs(0) and qs ready

  // --- gather q B-frags from qs into registers (once per block) ---
  // b-frag for K-step kk: lane holds B[k=32kk+8g+j][col=sl], j=0..7
  uint4 bq[8];
  #pragma unroll
  for (int kk = 0; kk < 8; ++kk){
    if (sl < 8){
      uint4 v;
      v.x = qs[(16*kk + 4*g + 0)*8 + sl];
      v.y = qs[(16*kk + 4*g + 1)*8 + sl];
      v.z = qs[(16*kk + 4*g + 2)*8 + sl];
      v.w = qs[(16*kk + 4*g + 3)*8 + sl];
      bq[kk] = v;
    } else bq[kk] = make_uint4(0u,0u,0u,0u);
  }
  const float cv = (sl < 8) ? cvec[b*8 + sl] : 0.f;

  float up[8][4];                         // [slot][col] register accumulators
  #pragma unroll
  for (int s = 0; s < 8; ++s){ up[s][0]=0.f; up[s][1]=0.f; up[s][2]=0.f; up[s][3]=0.f; }
  float asl_acc = 0.f;

  for (int st = 0; st < 4; ++st){
    if (st){ __syncthreads(); stage(st); __syncthreads(); }
    const int L0 = 16*w;

    // ---- logits tile [16 rows x 16 slots] via 8 MFMA K-steps ----
    f32x4 acc; acc[0]=0.f; acc[1]=0.f; acc[2]=0.f; acc[3]=0.f;
    const int rowA = L0 + sl;             // A-frag row (m = sl)
    #pragma unroll
    for (int kk = 0; kk < 8; ++kk){
      uint4 av = *(const uint4*)(xs + rowA*128 + (((4*kk + g) ^ (rowA & 7)) << 2));
      union { uint4 u; f16x8 h; } A, B;
      A.u = av; B.u = bq[kk];
      acc = __builtin_amdgcn_mfma_f32_16x16x32_f16(A.h, B.h, acc, 0, 0, 0);
    }

    // ---- softmax over slots: D lane holds (slot=sl, rows L0+4g+reg) ----
    #pragma unroll
    for (int reg = 0; reg < 4; ++reg){
      float d = (acc[reg] + cv) * 0.0625f;
      float m = d;
      m = fmaxf(m, __shfl_xor(m, 1));
      m = fmaxf(m, __shfl_xor(m, 2));
      m = fmaxf(m, __shfl_xor(m, 4));
      float e = __expf(d - m);
      float ssum = e;
      ssum += __shfl_xor(ssum, 1);
      ssum += __shfl_xor(ssum, 2);
      ssum += __shfl_xor(ssum, 4);
      float a = e / ssum + 1e-8f;
      asl_acc += a;                       // garbage for sl>=8, never used
      attn_lds[L0 + 4*g + reg][sl] = a;   // sl>=8 writes scratch cols
    }

    // ---- updates: wave w owns rows L0..L0+15; lane owns cols 4l..4l+3 ----
    // attn_lds rows written by THIS wave -> no barrier needed (lgkm only)
    #pragma unroll 4
    for (int rr = 0; rr < 16; ++rr){
      const int row = L0 + rr;
      const uint32_t* xp = xs + row*128 + ((((l>>1) ^ (row & 7)) << 2) | ((l & 1) << 1));
      uint2 xv = *(const uint2*)xp;
      float x0 = __half2float(__ushort_as_half((unsigned short)(xv.x & 0xffff)));
      float x1 = __half2float(__ushort_as_half((unsigned short)(xv.x >> 16)));
      float x2 = __half2float(__ushort_as_half((unsigned short)(xv.y & 0xffff)));
      float x3 = __half2float(__ushort_as_half((unsigned short)(xv.y >> 16)));
      const float4 a0 = *(const float4*)&attn_lds[row][0];
      const float4 a1 = *(const float4*)&attn_lds[row][4];
      float as8[8] = {a0.x, a0.y, a0.z, a0.w, a1.x, a1.y, a1.z, a1.w};
      #pragma unroll
      for (int s = 0; s < 8; ++s){
        up[s][0] += as8[s]*x0; up[s][1] += as8[s]*x1;
        up[s][2] += as8[s]*x2; up[s][3] += as8[s]*x3;
      }
    }

    if (LAST){
      __syncthreads();                    // all waves' attn_lds visible
      int row = t >> 2, s0 = (t & 3)*2;
      float2 v = *(const float2*)&attn_lds[row][s0];
      *(float2*)(attn_out + (base + (size_t)st*64 + row)*8 + s0) = v;
    }
  }

  // ---- asum partials: per-wave reduce over g, stash in LDS ----
  {
    float v = asl_acc;
    v += __shfl_xor(v, 16);
    v += __shfl_xor(v, 32);
    if (l < 8) as_red[w][l] = v;
  }

  // ---- cross-wave reduction of up into up_lds (4 turns), then plain stores ----
  __syncthreads();
  #pragma unroll
  for (int ww = 0; ww < 4; ++ww){
    if (w == ww){
      #pragma unroll
      for (int s = 0; s < 8; ++s){
        float4* dst = (float4*)&up_lds[s][l*4];
        float4 v = make_float4(up[s][0], up[s][1], up[s][2], up[s][3]);
        if (ww){ float4 o = *dst; v.x += o.x; v.y += o.y; v.z += o.z; v.w += o.w; }
        *dst = v;
      }
    }
    __syncthreads();
  }
  #pragma unroll
  for (int s = 0; s < 8; ++s)
    UAp[(size_t)chunk*65536 + (size_t)(b*8 + s)*256 + t] = up_lds[s][t];
  if (t < 8)
    ASp[chunk*256 + b*8 + t] = as_red[0][t] + as_red[1][t] + as_red[2][t] + as_red[3][t];
}

// ---------------- final output: attn renormalize only (slots written by k_slot<2>) ----------------
__global__ __launch_bounds__(256) void k_out(
  const float* __restrict__ AS, float* __restrict__ out)
{
  int j = blockIdx.x * 256 + threadIdx.x;   // 0..1048575
  int b = j >> 15;
  int s = j & 7;
  out[65536 + j] = out[65536 + j] * (1.0f / AS[b*8 + s]);
}

extern "C" void kernel_launch(void* const* d_in, const int* in_sizes, int n_in,
                              void* d_out, int out_size, void* d_ws, size_t ws_size,
                              hipStream_t stream) {
  const float* inputs = (const float*)d_in[0];
  const float* noise  = (const float*)d_in[1];
  const float* mu     = (const float*)d_in[2];
  const float* sigraw = (const float*)d_in[3];
  const float* lng    = (const float*)d_in[4];
  const float* lnb    = (const float*)d_in[5];
  const float* lsg    = (const float*)d_in[6];
  const float* lsb    = (const float*)d_in[7];
  const float* lmg    = (const float*)d_in[8];
  const float* lmb    = (const float*)d_in[9];
  const float* wq     = (const float*)d_in[10];
  const float* bq     = (const float*)d_in[11];
  const float* wk     = (const float*)d_in[12];
  const float* bk     = (const float*)d_in[13];
  const float* wv     = (const float*)d_in[14];
  const float* bv     = (const float*)d_in[15];
  const float* wih    = (const float*)d_in[16];
  const float* whh    = (const float*)d_in[17];
  const float* bih    = (const float*)d_in[18];
  const float* bhh    = (const float*)d_in[19];
  const float* w1     = (const float*)d_in[20];
  const float* b1     = (const float*)d_in[21];
  const float* w2     = (const float*)d_in[22];
  const float* b2     = (const float*)d_in[23];
  float* out = (float*)d_out;

  char* w = (char*)d_ws;
  size_t o = 0;
  uint32_t* XH = (uint32_t*)w;  o += 67108864;
  uint32_t* QT = (uint32_t*)(w + o); o += 131072;
  float* CV  = (float*)(w + o); o += 1024;
  float* AS  = (float*)(w + o); o += 1024;
  float* S0  = (float*)(w + o); o += 262144;
  uint4* WQp = (uint4*)(w + o); o += 131072;
  uint4* WVp = (uint4*)(w + o); o += 131072;
  uint4* WIHp= (uint4*)(w + o); o += 393216;
  uint4* WHHp= (uint4*)(w + o); o += 393216;
  uint4* W1p = (uint4*)(w + o); o += 262144;
  uint4* W2p = (uint4*)(w + o); o += 262144;
  uint4* WKp = (uint4*)(w + o); o += 131072;
  float* UAp = (float*)(w + o); o += 4194304;   // [16][256][256] f32
  float* ASp = (float*)(w + o); o += 16384;     // [16][256] f32

  k_lntr<<<33184, 256, 0, stream>>>(inputs, lng, lnb, XH,
                                    wq, wv, wih, whh, w1, w2, wk,
                                    WQp, WVp, WIHp, WHHp, W1p, W2p, WKp);
  k_slot<0><<<256, 512, 0, stream>>>(noise, mu, sigraw, S0, S0, UAp, ASp, AS,
      WVp, bv, WIHp, WHHp, bih, bhh, lmg, lmb, W1p, b1, W2p, b2,
      lsg, lsb, WQp, bq, WKp, bk, QT, CV);

  dim3 ga(16, 32);
  for (int it = 0; it < 3; ++it){
    if (it == 2) k_attn<true ><<<ga, 256, 0, stream>>>(XH, QT, CV, UAp, ASp, out + 65536);
    else         k_attn<false><<<ga, 256, 0, stream>>>(XH, QT, CV, UAp, ASp, out + 65536);
    if (it < 2)
      k_slot<1><<<256, 512, 0, stream>>>(noise, mu, sigraw, S0, S0, UAp, ASp, AS,
          WVp, bv, WIHp, WHHp, bih, bhh, lmg, lmb, W1p, b1, W2p, b2,
          lsg, lsb, WQp, bq, WKp, bk, QT, CV);
    else
      k_slot<2><<<256, 512, 0, stream>>>(noise, mu, sigraw, S0, out, UAp, ASp, AS,
          WVp, bv, WIHp, WHHp, bih, bhh, lmg, lmb, W1p, b1, W2p, b2,
          lsg, lsb, WQp, bq, WKp, bk, QT, CV);
  }
  k_out<<<4096, 256, 0, stream>>>(AS, out);
}